// Round 8
// baseline (182.423 us; speedup 1.0000x reference)
//
#include <hip/hip_runtime.h>
#include <hip/hip_bf16.h>
#include <hip/hip_fp16.h>

// Guided filter, B=8 C=3 H=W=512, RADIUS=15 (31x31 box, zero-pad, /961).
// R8: R7 + px-major uint4 H8 (one 16-B load per row-step in gfB instead of
//     4 plane-scattered dwords) and 2-col/thread gfC2 (uint2 loads) — the
//     V-pass kernels were latency-bound on narrow loads (R6 gfB: 49% peak,
//     VALUBusy 10%, occupancy 17%).
//   gfA : H-box 8 stage1 planes -> H8 uint4/px {g,g2|p0,gp0|p1,gp1|p2,gp2} + gray fp16
//   gfB : V-box (running column sums) + pointwise -> ab half2 {a,b}
//   gfC1: H-box of (a,b) -> abH half2
//   gfC2: V-box of (a,b) 2 cols/thread + gray + combine -> out f32
// ws layout: H8 32MiB | gray 4MiB | ab 24MiB | abH 24MiB = 84MiB.

#define HW 512
#define PLANE 262144
#define RAD 15
#define INV_K2 (1.0f / 961.0f)
#define LROW 584          // skewed row buffer: max SK(559)=576, padded

__device__ __forceinline__ int SK(int i) { return i + (i >> 5); }
__device__ __forceinline__ unsigned h2u(__half2 h) { return *(unsigned*)&h; }

// ---------------- gfA: H-pass of the 8 stage-1 planes + gray save ----------
// grid (1,128,8) x 256 (4 waves); wave w -> row y = by*4+w; lane l -> [8l,8l+8)
__global__ __launch_bounds__(256) void gfA(const float* __restrict__ guide,
                                           const float* __restrict__ inp,
                                           uint4* __restrict__ H8,
                                           __half* __restrict__ gray)
{
    __shared__ float lds[4][4 * LROW];
    const int tid = threadIdx.x, w = tid >> 6, l = tid & 63;
    const int y = blockIdx.y * 4 + w;
    const int b = blockIdx.z;

    float* LG  = lds[w];
    float* LP0 = LG + LROW;
    float* LP1 = LG + 2 * LROW;
    float* LP2 = LG + 3 * LROW;

    const float* gR = guide + (size_t)b * 3 * PLANE + y * HW;
    const float* gG = gR + PLANE;
    const float* gB = gR + 2 * PLANE;
    const float* q0 = inp + (size_t)b * 3 * PLANE + y * HW;
    const float* q1 = q0 + PLANE;
    const float* q2 = q0 + 2 * PLANE;
    __half* grow = gray + (size_t)b * PLANE + y * HW;

    const float4 z4 = make_float4(0.f, 0.f, 0.f, 0.f);

    // stage padded row (cols -16..543 -> idx 0..559), 140 float4 chunks
    #pragma unroll
    for (int rnd = 0; rnd < 3; ++rnd) {
        if (rnd < 2 || l < 12) {
            int q = l + rnd * 64;
            int col = 4 * q - 16;                    // mult of 4
            bool ok = (unsigned)col < (unsigned)HW;
            float4 r  = ok ? *(const float4*)(gR + col) : z4;
            float4 g  = ok ? *(const float4*)(gG + col) : z4;
            float4 bl = ok ? *(const float4*)(gB + col) : z4;
            float4 v0 = ok ? *(const float4*)(q0 + col) : z4;
            float4 v1 = ok ? *(const float4*)(q1 + col) : z4;
            float4 v2 = ok ? *(const float4*)(q2 + col) : z4;
            float l0 = 0.299f*r.x + 0.587f*g.x + 0.114f*bl.x;
            float l1 = 0.299f*r.y + 0.587f*g.y + 0.114f*bl.y;
            float l2 = 0.299f*r.z + 0.587f*g.z + 0.114f*bl.z;
            float l3 = 0.299f*r.w + 0.587f*g.w + 0.114f*bl.w;
            int i0 = 4 * q;
            LG[SK(i0+0)] = l0; LG[SK(i0+1)] = l1; LG[SK(i0+2)] = l2; LG[SK(i0+3)] = l3;
            LP0[SK(i0+0)] = v0.x; LP0[SK(i0+1)] = v0.y; LP0[SK(i0+2)] = v0.z; LP0[SK(i0+3)] = v0.w;
            LP1[SK(i0+0)] = v1.x; LP1[SK(i0+1)] = v1.y; LP1[SK(i0+2)] = v1.z; LP1[SK(i0+3)] = v1.w;
            LP2[SK(i0+0)] = v2.x; LP2[SK(i0+1)] = v2.y; LP2[SK(i0+2)] = v2.z; LP2[SK(i0+3)] = v2.w;
            if (ok) {       // save gray plane (center cols only) as fp16
                __half2* gp = (__half2*)(grow + col);
                gp[0] = __floats2half2_rn(l0, l1);
                gp[1] = __floats2half2_rn(l2, l3);
            }
        }
    }
    // no barrier: each wave touches only lds[w]

    const int t0 = 8 * l;      // output j taps: idx t0+j+1 .. t0+j+31
    unsigned up[4][8];         // 4 pair-planes x 8 px, packed half2

    {   // pair 0: {g, g^2}
        float s0 = 0.f, s1 = 0.f;
        #pragma unroll
        for (int k = 1; k <= 31; ++k) { float g = LG[SK(t0 + k)]; s0 += g; s1 += g * g; }
        up[0][0] = h2u(__floats2half2_rn(s0, s1));
        #pragma unroll
        for (int j = 1; j < 8; ++j) {
            float gi = LG[SK(t0 + j + 31)], go = LG[SK(t0 + j)];
            s0 += gi - go; s1 += gi * gi - go * go;
            up[0][j] = h2u(__floats2half2_rn(s0, s1));
        }
    }
#define PAIR_C(LP, c)                                                         \
    {                                                                         \
        float s0 = 0.f, s1 = 0.f;                                             \
        _Pragma("unroll")                                                     \
        for (int k = 1; k <= 31; ++k) {                                       \
            float g = LG[SK(t0 + k)], p = (LP)[SK(t0 + k)];                   \
            s0 += p; s1 += g * p;                                             \
        }                                                                     \
        up[1 + (c)][0] = h2u(__floats2half2_rn(s0, s1));                      \
        _Pragma("unroll")                                                     \
        for (int j = 1; j < 8; ++j) {                                         \
            float gi = LG[SK(t0 + j + 31)], go = LG[SK(t0 + j)];              \
            float pi = (LP)[SK(t0 + j + 31)], po = (LP)[SK(t0 + j)];          \
            s0 += pi - po; s1 += gi * pi - go * po;                           \
            up[1 + (c)][j] = h2u(__floats2half2_rn(s0, s1));                  \
        }                                                                     \
    }
    PAIR_C(LP0, 0)
    PAIR_C(LP1, 1)
    PAIR_C(LP2, 2)
#undef PAIR_C

    uint4* dst = H8 + (size_t)b * PLANE + y * HW + 8 * l;   // px-major
    #pragma unroll
    for (int j = 0; j < 8; ++j)
        dst[j] = make_uint4(up[0][j], up[1][j], up[2][j], up[3][j]);
}

// ---------------- gfB: V-pass + pointwise -> ab (half2) ----------------
// grid (2,32,8) x 256. thread = (b, x, 16-row strip). One uint4 load/row.
__global__ __launch_bounds__(256) void gfB(const uint4* __restrict__ H8,
                                           __half2* __restrict__ ab)
{
    const int x  = blockIdx.x * 256 + threadIdx.x;
    const int y0 = blockIdx.y * 16;
    const int b  = blockIdx.z;
    const uint4* base = H8 + (size_t)b * PLANE + x;

    float2 s[4];
    #pragma unroll
    for (int p = 0; p < 4; ++p) s[p] = make_float2(0.f, 0.f);

#define ACC(r, sgn)                                                          \
    {                                                                        \
        uint4 v = base[(r) * HW];                                            \
        float2 f0 = __half22float2(*(__half2*)&v.x);                         \
        float2 f1 = __half22float2(*(__half2*)&v.y);                         \
        float2 f2 = __half22float2(*(__half2*)&v.z);                         \
        float2 f3 = __half22float2(*(__half2*)&v.w);                         \
        s[0].x sgn f0.x; s[0].y sgn f0.y;                                    \
        s[1].x sgn f1.x; s[1].y sgn f1.y;                                    \
        s[2].x sgn f2.x; s[2].y sgn f2.y;                                    \
        s[3].x sgn f3.x; s[3].y sgn f3.y;                                    \
    }

    for (int r = y0 - RAD; r < y0 + RAD; ++r) {
        if ((unsigned)r < (unsigned)HW) ACC(r, +=)
    }
    __half2* ab0 = ab + (size_t)b * 3 * PLANE + x;
    #pragma unroll
    for (int i = 0; i < 16; ++i) {
        int y = y0 + i;
        int ra = y + RAD;
        if (ra < HW) ACC(ra, +=)
        float mI = s[0].x * INV_K2;
        float vI = s[0].y * INV_K2 - mI * mI;
        float rv = 1.0f / (vI + 1e-6f);
        #pragma unroll
        for (int c = 0; c < 3; ++c) {
            float mp   = s[1 + c].x * INV_K2;
            float corr = s[1 + c].y * INV_K2;
            float cov  = corr - mI * mp;
            float aa   = cov * rv;
            float bb   = mp - aa * mI;
            ab0[(size_t)c * PLANE + y * HW] = __floats2half2_rn(aa, bb);
        }
        int rs = y - RAD;
        if (rs >= 0) ACC(rs, -=)
    }
#undef ACC
}

// ---------------- gfC1: H-pass of (a,b) half2 ----------------
// grid (1,128,24) x 256 (4 waves); wave -> row; skewed LDS staging.
__global__ __launch_bounds__(256) void gfC1(const __half2* __restrict__ ab,
                                            __half2* __restrict__ abH)
{
    __shared__ float lds[4][2 * LROW];
    const int tid = threadIdx.x, w = tid >> 6, l = tid & 63;
    const int y  = blockIdx.y * 4 + w;
    const int bc = blockIdx.z;

    float* LA = lds[w];
    float* LB = LA + LROW;
    const __half2* src = ab + (size_t)bc * PLANE + y * HW;
    const float4 z4 = make_float4(0.f, 0.f, 0.f, 0.f);

    // stage 560 px: 140 chunks of 4 px (float4 = 4 half2)
    #pragma unroll
    for (int rnd = 0; rnd < 3; ++rnd) {
        if (rnd < 2 || l < 12) {
            int q = l + rnd * 64;
            int px = 4 * q - 16;
            bool ok = (unsigned)px < (unsigned)HW;
            float4 v = ok ? *(const float4*)(src + px) : z4;
            float2 f0 = __half22float2(*(__half2*)&v.x);
            float2 f1 = __half22float2(*(__half2*)&v.y);
            float2 f2 = __half22float2(*(__half2*)&v.z);
            float2 f3 = __half22float2(*(__half2*)&v.w);
            int i0 = 4 * q;
            LA[SK(i0+0)] = f0.x; LB[SK(i0+0)] = f0.y;
            LA[SK(i0+1)] = f1.x; LB[SK(i0+1)] = f1.y;
            LA[SK(i0+2)] = f2.x; LB[SK(i0+2)] = f2.y;
            LA[SK(i0+3)] = f3.x; LB[SK(i0+3)] = f3.y;
        }
    }

    const int t0 = 8 * l;
    float sa = 0.f, sb = 0.f, oa[8], ob[8];
    #pragma unroll
    for (int k = 1; k <= 31; ++k) { sa += LA[SK(t0 + k)]; sb += LB[SK(t0 + k)]; }
    oa[0] = sa; ob[0] = sb;
    #pragma unroll
    for (int j = 1; j < 8; ++j) {
        sa += LA[SK(t0 + j + 31)] - LA[SK(t0 + j)];
        sb += LB[SK(t0 + j + 31)] - LB[SK(t0 + j)];
        oa[j] = sa; ob[j] = sb;
    }
    unsigned u[8];
    #pragma unroll
    for (int j = 0; j < 8; ++j)
        u[j] = h2u(__floats2half2_rn(oa[j], ob[j]));
    uint4* dst = (uint4*)(abH + (size_t)bc * PLANE + y * HW + 8 * l);
    dst[0] = make_uint4(u[0], u[1], u[2], u[3]);
    dst[1] = make_uint4(u[4], u[5], u[6], u[7]);
}

// ---------------- gfC2: V-pass of (a,b), 2 cols/thread + gray + combine ----
// grid (1,32,24) x 256. lane handles cols 2t, 2t+1 via uint2 loads.
__global__ __launch_bounds__(256) void gfC2(const __half* __restrict__ gray,
                                            const __half2* __restrict__ abH,
                                            float* __restrict__ out)
{
    const int tid = threadIdx.x;
    const int y0 = blockIdx.y * 16;
    const int bc = blockIdx.z;
    const int b  = bc / 3;
    const __half2* srcp = abH + (size_t)bc * PLANE + 2 * tid;   // cols 2t,2t+1
    const __half2* gp2  = (const __half2*)(gray + (size_t)b * PLANE) + tid;
    float2* op2 = (float2*)(out + (size_t)bc * PLANE) + tid;

    float sa0 = 0.f, sb0 = 0.f, sa1 = 0.f, sb1 = 0.f;

#define ACC2(r, sgn)                                                         \
    {                                                                        \
        uint2 u = *(const uint2*)(srcp + (r) * HW);                          \
        float2 v0 = __half22float2(*(__half2*)&u.x);                         \
        float2 v1 = __half22float2(*(__half2*)&u.y);                         \
        sa0 sgn v0.x; sb0 sgn v0.y;                                          \
        sa1 sgn v1.x; sb1 sgn v1.y;                                          \
    }

    for (int r = y0 - RAD; r < y0 + RAD; ++r) {
        if ((unsigned)r < (unsigned)HW) ACC2(r, +=)
    }
    #pragma unroll
    for (int i = 0; i < 16; ++i) {
        int y = y0 + i;
        int ra = y + RAD;
        if (ra < HW) ACC2(ra, +=)
        float2 g = __half22float2(gp2[y * (HW / 2)]);
        op2[y * (HW / 2)] = make_float2(sa0 * INV_K2 * g.x + sb0 * INV_K2,
                                        sa1 * INV_K2 * g.y + sb1 * INV_K2);
        int rs = y - RAD;
        if (rs >= 0) ACC2(rs, -=)
    }
#undef ACC2
}

// ===================== fallback: R3 LDS-tiled path (50.3 MB ws) ==========

#define TILE 32
#define HAL 62
#define GS 63
#define SS 33

__global__ __launch_bounds__(256) void gf_s1_fb(
    const float* __restrict__ guide, const float* __restrict__ inp,
    float2* __restrict__ ab)
{
    __shared__ float gh[HAL * GS];
    __shared__ float ph[HAL * GS];
    __shared__ float h0[HAL * SS];
    __shared__ float h1[HAL * SS];

    const int tx0 = blockIdx.x * TILE;
    const int ty0 = blockIdx.y * TILE;
    const int b   = blockIdx.z;
    const int tid = threadIdx.x;

    const float* gbase = guide + (size_t)b * 3 * PLANE;
    const float* pbase = inp   + (size_t)b * 3 * PLANE;

    int lidx[16], goff[16];
    #pragma unroll
    for (int k = 0; k < 16; ++k) {
        int i = tid + k * 256;
        int r = i / HAL, c = i - r * HAL;
        bool inh = i < HAL * HAL;
        lidx[k] = inh ? (r * GS + c) : -1;
        int y = ty0 + r - RAD, x = tx0 + c - RAD;
        bool ok = inh && ((unsigned)y < (unsigned)HW) && ((unsigned)x < (unsigned)HW);
        goff[k] = ok ? (y * HW + x) : -1;
    }
    float gr_[16], pA[16];
    #pragma unroll
    for (int k = 0; k < 16; ++k) {
        float g = 0.f, p = 0.f;
        if (goff[k] >= 0) {
            int o = goff[k];
            g = 0.299f * gbase[o] + 0.587f * gbase[PLANE + o] + 0.114f * gbase[2 * PLANE + o];
            p = pbase[o];
        }
        gr_[k] = g; pA[k] = p;
    }
    #pragma unroll
    for (int k = 0; k < 16; ++k)
        if (lidx[k] >= 0) { gh[lidx[k]] = gr_[k]; ph[lidx[k]] = pA[k]; }
    __syncthreads();

    const int hr = tid & 63, hq = tid >> 6;
    const bool hact = hr < HAL;
    const int hbase = hr * GS + hq * 8;
    const int obase = hr * SS + hq * 8;
    const int vc = tid & 31, vq = tid >> 5;
    const int vbase = (vq * 4) * SS + vc;

    if (hact) {
        float s0 = 0.f, s1 = 0.f;
        #pragma unroll
        for (int k = 0; k < 31; ++k) { float v = gh[hbase + k]; s0 += v; s1 += v * v; }
        h0[obase] = s0; h1[obase] = s1;
        #pragma unroll
        for (int j = 1; j < 8; ++j) {
            float vi = gh[hbase + j + 30], vo = gh[hbase + j - 1];
            s0 += vi - vo; s1 += vi * vi - vo * vo;
            h0[obase + j] = s0; h1[obase + j] = s1;
        }
    }
    __syncthreads();

    float meanI[4], varI[4];
    {
        float s0 = 0.f, s1 = 0.f;
        #pragma unroll
        for (int k = 0; k < 31; ++k) { s0 += h0[vbase + k * SS]; s1 += h1[vbase + k * SS]; }
        meanI[0] = s0 * INV_K2; varI[0] = s1 * INV_K2 - meanI[0] * meanI[0];
        #pragma unroll
        for (int j = 1; j < 4; ++j) {
            s0 += h0[vbase + (j + 30) * SS] - h0[vbase + (j - 1) * SS];
            s1 += h1[vbase + (j + 30) * SS] - h1[vbase + (j - 1) * SS];
            meanI[j] = s0 * INV_K2; varI[j] = s1 * INV_K2 - meanI[j] * meanI[j];
        }
    }
    float pB[16];
    #pragma unroll
    for (int k = 0; k < 16; ++k)
        pB[k] = (goff[k] >= 0) ? pbase[PLANE + goff[k]] : 0.f;

#define CH_H_FB                                                              \
    if (hact) {                                                              \
        float s0 = 0.f, s1 = 0.f;                                            \
        _Pragma("unroll")                                                    \
        for (int k = 0; k < 31; ++k) {                                       \
            float p = ph[hbase + k], g = gh[hbase + k];                      \
            s0 += p; s1 += g * p;                                            \
        }                                                                    \
        h0[obase] = s0; h1[obase] = s1;                                      \
        _Pragma("unroll")                                                    \
        for (int j = 1; j < 8; ++j) {                                        \
            float pi = ph[hbase + j + 30], po = ph[hbase + j - 1];           \
            float gi = gh[hbase + j + 30], go = gh[hbase + j - 1];           \
            s0 += pi - po; s1 += gi * pi - go * po;                          \
            h0[obase + j] = s0; h1[obase + j] = s1;                          \
        }                                                                    \
    }
#define CH_V_FB(ch)                                                          \
    {                                                                        \
        float s0 = 0.f, s1 = 0.f;                                            \
        _Pragma("unroll")                                                    \
        for (int k = 0; k < 31; ++k) { s0 += h0[vbase + k * SS]; s1 += h1[vbase + k * SS]; } \
        float2* abp = ab + (size_t)(b * 3 + (ch)) * PLANE;                   \
        _Pragma("unroll")                                                    \
        for (int j = 0; j < 4; ++j) {                                        \
            if (j) {                                                         \
                s0 += h0[vbase + (j + 30) * SS] - h0[vbase + (j - 1) * SS];  \
                s1 += h1[vbase + (j + 30) * SS] - h1[vbase + (j - 1) * SS];  \
            }                                                                \
            float mp = s0 * INV_K2, corr = s1 * INV_K2;                      \
            float cov = corr - meanI[j] * mp;                                \
            float aa  = cov / (varI[j] + 1e-6f);                             \
            float bb  = mp - aa * meanI[j];                                  \
            abp[(ty0 + vq * 4 + j) * HW + tx0 + vc] = make_float2(aa, bb);   \
        }                                                                    \
    }

    __syncthreads();
    CH_H_FB
    __syncthreads();
    CH_V_FB(0)
    #pragma unroll
    for (int k = 0; k < 16; ++k) if (lidx[k] >= 0) ph[lidx[k]] = pB[k];
    float pC[16];
    #pragma unroll
    for (int k = 0; k < 16; ++k)
        pC[k] = (goff[k] >= 0) ? pbase[2 * PLANE + goff[k]] : 0.f;
    __syncthreads();
    CH_H_FB
    __syncthreads();
    CH_V_FB(1)
    #pragma unroll
    for (int k = 0; k < 16; ++k) if (lidx[k] >= 0) ph[lidx[k]] = pC[k];
    __syncthreads();
    CH_H_FB
    __syncthreads();
    CH_V_FB(2)
#undef CH_H_FB
#undef CH_V_FB
}

__global__ __launch_bounds__(256) void gf_s2_fb(
    const float* __restrict__ guide, const float2* __restrict__ ab,
    float* __restrict__ out)
{
    __shared__ float ah[HAL * GS];
    __shared__ float bh[HAL * GS];
    __shared__ float h0[HAL * SS];
    __shared__ float h1[HAL * SS];

    const int tx0 = blockIdx.x * TILE;
    const int ty0 = blockIdx.y * TILE;
    const int bc  = blockIdx.z;
    const int b   = bc / 3;
    const int tid = threadIdx.x;

    const float2* abp = ab + (size_t)bc * PLANE;
    const float*  gb  = guide + (size_t)b * 3 * PLANE;
    const int vc = tid & 31, vq = tid >> 5;

    int lidx[16];
    float2 hv[16];
    #pragma unroll
    for (int k = 0; k < 16; ++k) {
        int i = tid + k * 256;
        int r = i / HAL, c = i - r * HAL;
        bool inh = i < HAL * HAL;
        lidx[k] = inh ? (r * GS + c) : -1;
        int y = ty0 + r - RAD, x = tx0 + c - RAD;
        bool ok = inh && ((unsigned)y < (unsigned)HW) && ((unsigned)x < (unsigned)HW);
        hv[k] = ok ? abp[y * HW + x] : make_float2(0.f, 0.f);
    }
    float gcen[4];
    #pragma unroll
    for (int j = 0; j < 4; ++j) {
        int o = (ty0 + vq * 4 + j) * HW + tx0 + vc;
        gcen[j] = 0.299f * gb[o] + 0.587f * gb[PLANE + o] + 0.114f * gb[2 * PLANE + o];
    }
    #pragma unroll
    for (int k = 0; k < 16; ++k)
        if (lidx[k] >= 0) { ah[lidx[k]] = hv[k].x; bh[lidx[k]] = hv[k].y; }
    __syncthreads();

    const int hr = tid & 63, hq = tid >> 6;
    const int hbase = hr * GS + hq * 8;
    const int obase = hr * SS + hq * 8;
    if (hr < HAL) {
        float s0 = 0.f, s1 = 0.f;
        #pragma unroll
        for (int k = 0; k < 31; ++k) { s0 += ah[hbase + k]; s1 += bh[hbase + k]; }
        h0[obase] = s0; h1[obase] = s1;
        #pragma unroll
        for (int j = 1; j < 8; ++j) {
            s0 += ah[hbase + j + 30] - ah[hbase + j - 1];
            s1 += bh[hbase + j + 30] - bh[hbase + j - 1];
            h0[obase + j] = s0; h1[obase + j] = s1;
        }
    }
    __syncthreads();
    {
        const int vbase = (vq * 4) * SS + vc;
        float s0 = 0.f, s1 = 0.f;
        #pragma unroll
        for (int k = 0; k < 31; ++k) { s0 += h0[vbase + k * SS]; s1 += h1[vbase + k * SS]; }
        float* op = out + (size_t)bc * PLANE;
        #pragma unroll
        for (int j = 0; j < 4; ++j) {
            if (j) {
                s0 += h0[vbase + (j + 30) * SS] - h0[vbase + (j - 1) * SS];
                s1 += h1[vbase + (j + 30) * SS] - h1[vbase + (j - 1) * SS];
            }
            int o = (ty0 + vq * 4 + j) * HW + tx0 + vc;
            op[o] = s0 * INV_K2 * gcen[j] + s1 * INV_K2;
        }
    }
}

// ===================== launch =====================

extern "C" void kernel_launch(void* const* d_in, const int* in_sizes, int n_in,
                              void* d_out, int out_size, void* d_ws, size_t ws_size,
                              hipStream_t stream)
{
    const float* guide = (const float*)d_in[0];
    const float* inp   = (const float*)d_in[1];
    float* out = (float*)d_out;

    const size_t H8_B   = (size_t)8 * PLANE * 16;      // 32 MiB (uint4/px)
    const size_t GRAY_B = (size_t)8 * PLANE * 2;       //  4 MiB
    const size_t AB_B   = (size_t)24 * PLANE * 4;      // 24 MiB
    const size_t ABH_B  = (size_t)24 * PLANE * 4;      // 24 MiB

    if (ws_size >= H8_B + GRAY_B + AB_B + ABH_B) {
        uint4*   H8   = (uint4*)d_ws;
        __half*  gray = (__half*)((char*)d_ws + H8_B);
        __half2* ab   = (__half2*)((char*)d_ws + H8_B + GRAY_B);
        __half2* abH  = (__half2*)((char*)d_ws + H8_B + GRAY_B + AB_B);

        gfA <<<dim3(1, 128,  8), 256, 0, stream>>>(guide, inp, H8, gray);
        gfB <<<dim3(2,  32,  8), 256, 0, stream>>>(H8, ab);
        gfC1<<<dim3(1, 128, 24), 256, 0, stream>>>(ab, abH);
        gfC2<<<dim3(1,  32, 24), 256, 0, stream>>>(gray, abH, out);
    } else {
        float2* ab_ws = (float2*)d_ws;   // 50.3 MB
        gf_s1_fb<<<dim3(HW / TILE, HW / TILE, 8),  256, 0, stream>>>(guide, inp, ab_ws);
        gf_s2_fb<<<dim3(HW / TILE, HW / TILE, 24), 256, 0, stream>>>(guide, ab_ws, out);
    }
}

// Round 9
// 172.918 us; speedup vs baseline: 1.0550x; 1.0550x over previous
//
#include <hip/hip_runtime.h>
#include <hip/hip_bf16.h>
#include <hip/hip_fp16.h>

// Guided filter, B=8 C=3 H=W=512, RADIUS=15 (31x31 box, zero-pad, /961).
// R9: R8 structure with three latency/coalescing fixes:
//  - gfA stages via explicit 18-load prefetch (1 HBM latency, not 3)
//  - gfA/gfC1 emit fully-coalesced uint4 stores via LDS stash-redistribute
//    (stash each pair into the staging region that just went dead)
//  - gfB/gfC2 prologues unrolled so row loads pipeline
//   gfA : H-box 8 stage1 planes -> H8 uint4/px {g,g2|p0,gp0|p1,gp1|p2,gp2} + gray fp16
//   gfB : V-box (running column sums) + pointwise -> ab half2 {a,b}
//   gfC1: H-box of (a,b) -> abH half2
//   gfC2: V-box of (a,b) 2 cols/thread + gray + combine -> out f32

#define HW 512
#define PLANE 262144
#define RAD 15
#define INV_K2 (1.0f / 961.0f)
#define LROW 584          // skewed row buffer: max SK(559)=576, padded

__device__ __forceinline__ int SK(int i) { return i + (i >> 5); }
__device__ __forceinline__ unsigned h2u(__half2 h) { return *(unsigned*)&h; }
__device__ __forceinline__ unsigned pk(float a, float b) {
    return h2u(__floats2half2_rn(a, b));
}

// ---------------- gfA: H-pass of the 8 stage-1 planes + gray save ----------
// grid (1,128,8) x 256 (4 waves); wave w -> row y = by*4+w; lane l -> [8l,8l+8)
__global__ __launch_bounds__(256) void gfA(const float* __restrict__ guide,
                                           const float* __restrict__ inp,
                                           uint4* __restrict__ H8,
                                           __half* __restrict__ gray)
{
    __shared__ float lds[4][4 * LROW];
    const int tid = threadIdx.x, w = tid >> 6, l = tid & 63;
    const int y = blockIdx.y * 4 + w;
    const int b = blockIdx.z;

    float* LG  = lds[w];
    float* LP0 = LG + LROW;
    float* LP1 = LG + 2 * LROW;
    float* LP2 = LG + 3 * LROW;

    const float* gR = guide + (size_t)b * 3 * PLANE + y * HW;
    const float* gG = gR + PLANE;
    const float* gB = gR + 2 * PLANE;
    const float* q0 = inp + (size_t)b * 3 * PLANE + y * HW;
    const float* q1 = q0 + PLANE;
    const float* q2 = q0 + 2 * PLANE;

    const float4 z4 = make_float4(0.f, 0.f, 0.f, 0.f);

    // ---- explicit prefetch: all 18 loads issued before any LDS write ----
    float4 vR[3], vG[3], vB[3], v0[3], v1[3], v2[3];
    #pragma unroll
    for (int rnd = 0; rnd < 3; ++rnd) {
        int q = l + rnd * 64;
        int col = 4 * q - 16;                        // mult of 4
        bool act = (rnd < 2 || l < 12) && ((unsigned)col < (unsigned)HW);
        vR[rnd] = act ? *(const float4*)(gR + col) : z4;
        vG[rnd] = act ? *(const float4*)(gG + col) : z4;
        vB[rnd] = act ? *(const float4*)(gB + col) : z4;
        v0[rnd] = act ? *(const float4*)(q0 + col) : z4;
        v1[rnd] = act ? *(const float4*)(q1 + col) : z4;
        v2[rnd] = act ? *(const float4*)(q2 + col) : z4;
    }
    #pragma unroll
    for (int rnd = 0; rnd < 3; ++rnd) {
        if (rnd < 2 || l < 12) {
            int q = l + rnd * 64;
            int i0 = 4 * q;
            float4 r = vR[rnd], g = vG[rnd], bl = vB[rnd];
            LG[SK(i0+0)] = 0.299f*r.x + 0.587f*g.x + 0.114f*bl.x;
            LG[SK(i0+1)] = 0.299f*r.y + 0.587f*g.y + 0.114f*bl.y;
            LG[SK(i0+2)] = 0.299f*r.z + 0.587f*g.z + 0.114f*bl.z;
            LG[SK(i0+3)] = 0.299f*r.w + 0.587f*g.w + 0.114f*bl.w;
            LP0[SK(i0+0)] = v0[rnd].x; LP0[SK(i0+1)] = v0[rnd].y;
            LP0[SK(i0+2)] = v0[rnd].z; LP0[SK(i0+3)] = v0[rnd].w;
            LP1[SK(i0+0)] = v1[rnd].x; LP1[SK(i0+1)] = v1[rnd].y;
            LP1[SK(i0+2)] = v1[rnd].z; LP1[SK(i0+3)] = v1[rnd].w;
            LP2[SK(i0+0)] = v2[rnd].x; LP2[SK(i0+1)] = v2[rnd].y;
            LP2[SK(i0+2)] = v2[rnd].z; LP2[SK(i0+3)] = v2[rnd].w;
        }
    }
    // no barrier: each wave touches only lds[w]

    const int t0 = 8 * l;      // output j taps: idx t0+j+1 .. t0+j+31
    unsigned uA[8], uB[8];

    {   // pair0: {g, g^2} -> uA
        float s0 = 0.f, s1 = 0.f;
        #pragma unroll
        for (int k = 1; k <= 31; ++k) { float g = LG[SK(t0 + k)]; s0 += g; s1 += g * g; }
        uA[0] = pk(s0, s1);
        #pragma unroll
        for (int j = 1; j < 8; ++j) {
            float gi = LG[SK(t0 + j + 31)], go = LG[SK(t0 + j)];
            s0 += gi - go; s1 += gi * gi - go * go;
            uA[j] = pk(s0, s1);
        }
    }
#define PAIR_C(LP, U)                                                         \
    {                                                                         \
        float s0 = 0.f, s1 = 0.f;                                             \
        _Pragma("unroll")                                                     \
        for (int k = 1; k <= 31; ++k) {                                       \
            float g = LG[SK(t0 + k)], p = (LP)[SK(t0 + k)];                   \
            s0 += p; s1 += g * p;                                             \
        }                                                                     \
        U[0] = pk(s0, s1);                                                    \
        _Pragma("unroll")                                                     \
        for (int j = 1; j < 8; ++j) {                                         \
            float gi = LG[SK(t0 + j + 31)], go = LG[SK(t0 + j)];              \
            float pi = (LP)[SK(t0 + j + 31)], po = (LP)[SK(t0 + j)];          \
            s0 += pi - po; s1 += gi * pi - go * po;                           \
            U[j] = pk(s0, s1);                                                \
        }                                                                     \
    }
#define STASH(REG, U)                                                         \
    _Pragma("unroll")                                                         \
    for (int j = 0; j < 8; ++j) (REG)[SK(t0 + j)] = __uint_as_float(U[j]);

    PAIR_C(LP0, uB)            // pair1 (ch0) — LP0 now dead
    STASH(LP0, uA)             // stash pair0
    PAIR_C(LP1, uA)            // pair2 (ch1) — LP1 dead
    STASH(LP1, uB)             // stash pair1
    PAIR_C(LP2, uB)            // pair3 (ch2) — LP2 dead
    STASH(LP2, uA)             // stash pair2

    {   // gray (center luma) — coalesced 16B/lane, read LG before overwrite
        float g0 = LG[SK(t0 + 16)], g1 = LG[SK(t0 + 17)];
        float g2 = LG[SK(t0 + 18)], g3 = LG[SK(t0 + 19)];
        float g4 = LG[SK(t0 + 20)], g5 = LG[SK(t0 + 21)];
        float g6 = LG[SK(t0 + 22)], g7 = LG[SK(t0 + 23)];
        __half* grow = gray + (size_t)b * PLANE + y * HW;
        *(uint4*)(grow + t0) = make_uint4(pk(g0, g1), pk(g2, g3),
                                          pk(g4, g5), pk(g6, g7));
    }
    STASH(LG, uB)              // stash pair3
#undef PAIR_C
#undef STASH

    // ---- readback px-major (conflict-free) -> fully coalesced uint4 stores
    uint4* H8row = H8 + (size_t)b * PLANE + y * HW;
    #pragma unroll
    for (int k = 0; k < 8; ++k) {
        int px = 64 * k + l;
        uint4 v;
        v.x = __float_as_uint(LP0[SK(px)]);
        v.y = __float_as_uint(LP1[SK(px)]);
        v.z = __float_as_uint(LP2[SK(px)]);
        v.w = __float_as_uint(LG[SK(px)]);
        H8row[px] = v;
    }
}

// ---------------- gfB: V-pass + pointwise -> ab (half2) ----------------
// grid (2,32,8) x 256. thread = (b, x, 16-row strip). One uint4 load/row.
__global__ __launch_bounds__(256) void gfB(const uint4* __restrict__ H8,
                                           __half2* __restrict__ ab)
{
    const int x  = blockIdx.x * 256 + threadIdx.x;
    const int y0 = blockIdx.y * 16;
    const int b  = blockIdx.z;
    const uint4* base = H8 + (size_t)b * PLANE + x;

    float2 s[4];
    #pragma unroll
    for (int p = 0; p < 4; ++p) s[p] = make_float2(0.f, 0.f);

#define ACC(r, sgn)                                                          \
    {                                                                        \
        uint4 v = base[(r) * HW];                                            \
        float2 f0 = __half22float2(*(__half2*)&v.x);                         \
        float2 f1 = __half22float2(*(__half2*)&v.y);                         \
        float2 f2 = __half22float2(*(__half2*)&v.z);                         \
        float2 f3 = __half22float2(*(__half2*)&v.w);                         \
        s[0].x sgn f0.x; s[0].y sgn f0.y;                                    \
        s[1].x sgn f1.x; s[1].y sgn f1.y;                                    \
        s[2].x sgn f2.x; s[2].y sgn f2.y;                                    \
        s[3].x sgn f3.x; s[3].y sgn f3.y;                                    \
    }

    #pragma unroll
    for (int dr = -RAD; dr < RAD; ++dr) {
        int r = y0 + dr;
        if ((unsigned)r < (unsigned)HW) ACC(r, +=)
    }
    __half2* ab0 = ab + (size_t)b * 3 * PLANE + x;
    #pragma unroll
    for (int i = 0; i < 16; ++i) {
        int y = y0 + i;
        int ra = y + RAD;
        if (ra < HW) ACC(ra, +=)
        float mI = s[0].x * INV_K2;
        float vI = s[0].y * INV_K2 - mI * mI;
        float rv = 1.0f / (vI + 1e-6f);
        #pragma unroll
        for (int c = 0; c < 3; ++c) {
            float mp   = s[1 + c].x * INV_K2;
            float corr = s[1 + c].y * INV_K2;
            float cov  = corr - mI * mp;
            float aa   = cov * rv;
            float bb   = mp - aa * mI;
            ab0[(size_t)c * PLANE + y * HW] = __floats2half2_rn(aa, bb);
        }
        int rs = y - RAD;
        if (rs >= 0) ACC(rs, -=)
    }
#undef ACC
}

// ---------------- gfC1: H-pass of (a,b) half2 ----------------
// grid (1,128,24) x 256 (4 waves); wave -> row; skewed LDS staging.
__global__ __launch_bounds__(256) void gfC1(const __half2* __restrict__ ab,
                                            __half2* __restrict__ abH)
{
    __shared__ float lds[4][2 * LROW];
    const int tid = threadIdx.x, w = tid >> 6, l = tid & 63;
    const int y  = blockIdx.y * 4 + w;
    const int bc = blockIdx.z;

    float* LA = lds[w];
    float* LB = LA + LROW;
    const __half2* src = ab + (size_t)bc * PLANE + y * HW;
    const float4 z4 = make_float4(0.f, 0.f, 0.f, 0.f);

    // explicit prefetch of the 3 staging loads
    float4 vs[3];
    #pragma unroll
    for (int rnd = 0; rnd < 3; ++rnd) {
        int q = l + rnd * 64;
        int px = 4 * q - 16;
        bool act = (rnd < 2 || l < 12) && ((unsigned)px < (unsigned)HW);
        vs[rnd] = act ? *(const float4*)(src + px) : z4;
    }
    #pragma unroll
    for (int rnd = 0; rnd < 3; ++rnd) {
        if (rnd < 2 || l < 12) {
            int q = l + rnd * 64;
            int i0 = 4 * q;
            float4 v = vs[rnd];
            float2 f0 = __half22float2(*(__half2*)&v.x);
            float2 f1 = __half22float2(*(__half2*)&v.y);
            float2 f2 = __half22float2(*(__half2*)&v.z);
            float2 f3 = __half22float2(*(__half2*)&v.w);
            LA[SK(i0+0)] = f0.x; LB[SK(i0+0)] = f0.y;
            LA[SK(i0+1)] = f1.x; LB[SK(i0+1)] = f1.y;
            LA[SK(i0+2)] = f2.x; LB[SK(i0+2)] = f2.y;
            LA[SK(i0+3)] = f3.x; LB[SK(i0+3)] = f3.y;
        }
    }

    const int t0 = 8 * l;
    float sa = 0.f, sb = 0.f;
    unsigned u[8];
    #pragma unroll
    for (int k = 1; k <= 31; ++k) { sa += LA[SK(t0 + k)]; sb += LB[SK(t0 + k)]; }
    u[0] = pk(sa, sb);
    #pragma unroll
    for (int j = 1; j < 8; ++j) {
        sa += LA[SK(t0 + j + 31)] - LA[SK(t0 + j)];
        sb += LB[SK(t0 + j + 31)] - LB[SK(t0 + j)];
        u[j] = pk(sa, sb);
    }
    // stash into LA (dead after slides), read back px-consecutive, store coalesced
    #pragma unroll
    for (int j = 0; j < 8; ++j) LA[SK(t0 + j)] = __uint_as_float(u[j]);
    uint4* dst = (uint4*)(abH + (size_t)bc * PLANE + y * HW);
    #pragma unroll
    for (int m = 0; m < 2; ++m) {
        int p0 = 256 * m + 4 * l;
        uint4 v;
        v.x = __float_as_uint(LA[SK(p0 + 0)]);
        v.y = __float_as_uint(LA[SK(p0 + 1)]);
        v.z = __float_as_uint(LA[SK(p0 + 2)]);
        v.w = __float_as_uint(LA[SK(p0 + 3)]);
        dst[64 * m + l] = v;
    }
}

// ---------------- gfC2: V-pass of (a,b), 2 cols/thread + gray + combine ----
// grid (1,32,24) x 256. lane handles cols 2t, 2t+1 via uint2 loads.
__global__ __launch_bounds__(256) void gfC2(const __half* __restrict__ gray,
                                            const __half2* __restrict__ abH,
                                            float* __restrict__ out)
{
    const int tid = threadIdx.x;
    const int y0 = blockIdx.y * 16;
    const int bc = blockIdx.z;
    const int b  = bc / 3;
    const __half2* srcp = abH + (size_t)bc * PLANE + 2 * tid;   // cols 2t,2t+1
    const __half2* gp2  = (const __half2*)(gray + (size_t)b * PLANE) + tid;
    float2* op2 = (float2*)(out + (size_t)bc * PLANE) + tid;

    float sa0 = 0.f, sb0 = 0.f, sa1 = 0.f, sb1 = 0.f;

#define ACC2(r, sgn)                                                         \
    {                                                                        \
        uint2 u = *(const uint2*)(srcp + (r) * HW);                          \
        float2 v0 = __half22float2(*(__half2*)&u.x);                         \
        float2 v1 = __half22float2(*(__half2*)&u.y);                         \
        sa0 sgn v0.x; sb0 sgn v0.y;                                          \
        sa1 sgn v1.x; sb1 sgn v1.y;                                          \
    }

    #pragma unroll
    for (int dr = -RAD; dr < RAD; ++dr) {
        int r = y0 + dr;
        if ((unsigned)r < (unsigned)HW) ACC2(r, +=)
    }
    #pragma unroll
    for (int i = 0; i < 16; ++i) {
        int y = y0 + i;
        int ra = y + RAD;
        if (ra < HW) ACC2(ra, +=)
        float2 g = __half22float2(gp2[y * (HW / 2)]);
        op2[y * (HW / 2)] = make_float2(sa0 * INV_K2 * g.x + sb0 * INV_K2,
                                        sa1 * INV_K2 * g.y + sb1 * INV_K2);
        int rs = y - RAD;
        if (rs >= 0) ACC2(rs, -=)
    }
#undef ACC2
}

// ===================== fallback: R3 LDS-tiled path (50.3 MB ws) ==========

#define TILE 32
#define HAL 62
#define GS 63
#define SS 33

__global__ __launch_bounds__(256) void gf_s1_fb(
    const float* __restrict__ guide, const float* __restrict__ inp,
    float2* __restrict__ ab)
{
    __shared__ float gh[HAL * GS];
    __shared__ float ph[HAL * GS];
    __shared__ float h0[HAL * SS];
    __shared__ float h1[HAL * SS];

    const int tx0 = blockIdx.x * TILE;
    const int ty0 = blockIdx.y * TILE;
    const int b   = blockIdx.z;
    const int tid = threadIdx.x;

    const float* gbase = guide + (size_t)b * 3 * PLANE;
    const float* pbase = inp   + (size_t)b * 3 * PLANE;

    int lidx[16], goff[16];
    #pragma unroll
    for (int k = 0; k < 16; ++k) {
        int i = tid + k * 256;
        int r = i / HAL, c = i - r * HAL;
        bool inh = i < HAL * HAL;
        lidx[k] = inh ? (r * GS + c) : -1;
        int y = ty0 + r - RAD, x = tx0 + c - RAD;
        bool ok = inh && ((unsigned)y < (unsigned)HW) && ((unsigned)x < (unsigned)HW);
        goff[k] = ok ? (y * HW + x) : -1;
    }
    float gr_[16], pA[16];
    #pragma unroll
    for (int k = 0; k < 16; ++k) {
        float g = 0.f, p = 0.f;
        if (goff[k] >= 0) {
            int o = goff[k];
            g = 0.299f * gbase[o] + 0.587f * gbase[PLANE + o] + 0.114f * gbase[2 * PLANE + o];
            p = pbase[o];
        }
        gr_[k] = g; pA[k] = p;
    }
    #pragma unroll
    for (int k = 0; k < 16; ++k)
        if (lidx[k] >= 0) { gh[lidx[k]] = gr_[k]; ph[lidx[k]] = pA[k]; }
    __syncthreads();

    const int hr = tid & 63, hq = tid >> 6;
    const bool hact = hr < HAL;
    const int hbase = hr * GS + hq * 8;
    const int obase = hr * SS + hq * 8;
    const int vc = tid & 31, vq = tid >> 5;
    const int vbase = (vq * 4) * SS + vc;

    if (hact) {
        float s0 = 0.f, s1 = 0.f;
        #pragma unroll
        for (int k = 0; k < 31; ++k) { float v = gh[hbase + k]; s0 += v; s1 += v * v; }
        h0[obase] = s0; h1[obase] = s1;
        #pragma unroll
        for (int j = 1; j < 8; ++j) {
            float vi = gh[hbase + j + 30], vo = gh[hbase + j - 1];
            s0 += vi - vo; s1 += vi * vi - vo * vo;
            h0[obase + j] = s0; h1[obase + j] = s1;
        }
    }
    __syncthreads();

    float meanI[4], varI[4];
    {
        float s0 = 0.f, s1 = 0.f;
        #pragma unroll
        for (int k = 0; k < 31; ++k) { s0 += h0[vbase + k * SS]; s1 += h1[vbase + k * SS]; }
        meanI[0] = s0 * INV_K2; varI[0] = s1 * INV_K2 - meanI[0] * meanI[0];
        #pragma unroll
        for (int j = 1; j < 4; ++j) {
            s0 += h0[vbase + (j + 30) * SS] - h0[vbase + (j - 1) * SS];
            s1 += h1[vbase + (j + 30) * SS] - h1[vbase + (j - 1) * SS];
            meanI[j] = s0 * INV_K2; varI[j] = s1 * INV_K2 - meanI[j] * meanI[j];
        }
    }
    float pB[16];
    #pragma unroll
    for (int k = 0; k < 16; ++k)
        pB[k] = (goff[k] >= 0) ? pbase[PLANE + goff[k]] : 0.f;

#define CH_H_FB                                                              \
    if (hact) {                                                              \
        float s0 = 0.f, s1 = 0.f;                                            \
        _Pragma("unroll")                                                    \
        for (int k = 0; k < 31; ++k) {                                       \
            float p = ph[hbase + k], g = gh[hbase + k];                      \
            s0 += p; s1 += g * p;                                            \
        }                                                                    \
        h0[obase] = s0; h1[obase] = s1;                                      \
        _Pragma("unroll")                                                    \
        for (int j = 1; j < 8; ++j) {                                        \
            float pi = ph[hbase + j + 30], po = ph[hbase + j - 1];           \
            float gi = gh[hbase + j + 30], go = gh[hbase + j - 1];           \
            s0 += pi - po; s1 += gi * pi - go * po;                          \
            h0[obase + j] = s0; h1[obase + j] = s1;                          \
        }                                                                    \
    }
#define CH_V_FB(ch)                                                          \
    {                                                                        \
        float s0 = 0.f, s1 = 0.f;                                            \
        _Pragma("unroll")                                                    \
        for (int k = 0; k < 31; ++k) { s0 += h0[vbase + k * SS]; s1 += h1[vbase + k * SS]; } \
        float2* abp = ab + (size_t)(b * 3 + (ch)) * PLANE;                   \
        _Pragma("unroll")                                                    \
        for (int j = 0; j < 4; ++j) {                                        \
            if (j) {                                                         \
                s0 += h0[vbase + (j + 30) * SS] - h0[vbase + (j - 1) * SS];  \
                s1 += h1[vbase + (j + 30) * SS] - h1[vbase + (j - 1) * SS];  \
            }                                                                \
            float mp = s0 * INV_K2, corr = s1 * INV_K2;                      \
            float cov = corr - meanI[j] * mp;                                \
            float aa  = cov / (varI[j] + 1e-6f);                             \
            float bb  = mp - aa * meanI[j];                                  \
            abp[(ty0 + vq * 4 + j) * HW + tx0 + vc] = make_float2(aa, bb);   \
        }                                                                    \
    }

    __syncthreads();
    CH_H_FB
    __syncthreads();
    CH_V_FB(0)
    #pragma unroll
    for (int k = 0; k < 16; ++k) if (lidx[k] >= 0) ph[lidx[k]] = pB[k];
    float pC[16];
    #pragma unroll
    for (int k = 0; k < 16; ++k)
        pC[k] = (goff[k] >= 0) ? pbase[2 * PLANE + goff[k]] : 0.f;
    __syncthreads();
    CH_H_FB
    __syncthreads();
    CH_V_FB(1)
    #pragma unroll
    for (int k = 0; k < 16; ++k) if (lidx[k] >= 0) ph[lidx[k]] = pC[k];
    __syncthreads();
    CH_H_FB
    __syncthreads();
    CH_V_FB(2)
#undef CH_H_FB
#undef CH_V_FB
}

__global__ __launch_bounds__(256) void gf_s2_fb(
    const float* __restrict__ guide, const float2* __restrict__ ab,
    float* __restrict__ out)
{
    __shared__ float ah[HAL * GS];
    __shared__ float bh[HAL * GS];
    __shared__ float h0[HAL * SS];
    __shared__ float h1[HAL * SS];

    const int tx0 = blockIdx.x * TILE;
    const int ty0 = blockIdx.y * TILE;
    const int bc  = blockIdx.z;
    const int b   = bc / 3;
    const int tid = threadIdx.x;

    const float2* abp = ab + (size_t)bc * PLANE;
    const float*  gb  = guide + (size_t)b * 3 * PLANE;
    const int vc = tid & 31, vq = tid >> 5;

    int lidx[16];
    float2 hv[16];
    #pragma unroll
    for (int k = 0; k < 16; ++k) {
        int i = tid + k * 256;
        int r = i / HAL, c = i - r * HAL;
        bool inh = i < HAL * HAL;
        lidx[k] = inh ? (r * GS + c) : -1;
        int y = ty0 + r - RAD, x = tx0 + c - RAD;
        bool ok = inh && ((unsigned)y < (unsigned)HW) && ((unsigned)x < (unsigned)HW);
        hv[k] = ok ? abp[y * HW + x] : make_float2(0.f, 0.f);
    }
    float gcen[4];
    #pragma unroll
    for (int j = 0; j < 4; ++j) {
        int o = (ty0 + vq * 4 + j) * HW + tx0 + vc;
        gcen[j] = 0.299f * gb[o] + 0.587f * gb[PLANE + o] + 0.114f * gb[2 * PLANE + o];
    }
    #pragma unroll
    for (int k = 0; k < 16; ++k)
        if (lidx[k] >= 0) { ah[lidx[k]] = hv[k].x; bh[lidx[k]] = hv[k].y; }
    __syncthreads();

    const int hr = tid & 63, hq = tid >> 6;
    const int hbase = hr * GS + hq * 8;
    const int obase = hr * SS + hq * 8;
    if (hr < HAL) {
        float s0 = 0.f, s1 = 0.f;
        #pragma unroll
        for (int k = 0; k < 31; ++k) { s0 += ah[hbase + k]; s1 += bh[hbase + k]; }
        h0[obase] = s0; h1[obase] = s1;
        #pragma unroll
        for (int j = 1; j < 8; ++j) {
            s0 += ah[hbase + j + 30] - ah[hbase + j - 1];
            s1 += bh[hbase + j + 30] - bh[hbase + j - 1];
            h0[obase + j] = s0; h1[obase + j] = s1;
        }
    }
    __syncthreads();
    {
        const int vbase = (vq * 4) * SS + vc;
        float s0 = 0.f, s1 = 0.f;
        #pragma unroll
        for (int k = 0; k < 31; ++k) { s0 += h0[vbase + k * SS]; s1 += h1[vbase + k * SS]; }
        float* op = out + (size_t)bc * PLANE;
        #pragma unroll
        for (int j = 0; j < 4; ++j) {
            if (j) {
                s0 += h0[vbase + (j + 30) * SS] - h0[vbase + (j - 1) * SS];
                s1 += h1[vbase + (j + 30) * SS] - h1[vbase + (j - 1) * SS];
            }
            int o = (ty0 + vq * 4 + j) * HW + tx0 + vc;
            op[o] = s0 * INV_K2 * gcen[j] + s1 * INV_K2;
        }
    }
}

// ===================== launch =====================

extern "C" void kernel_launch(void* const* d_in, const int* in_sizes, int n_in,
                              void* d_out, int out_size, void* d_ws, size_t ws_size,
                              hipStream_t stream)
{
    const float* guide = (const float*)d_in[0];
    const float* inp   = (const float*)d_in[1];
    float* out = (float*)d_out;

    const size_t H8_B   = (size_t)8 * PLANE * 16;      // 32 MiB (uint4/px)
    const size_t GRAY_B = (size_t)8 * PLANE * 2;       //  4 MiB
    const size_t AB_B   = (size_t)24 * PLANE * 4;      // 24 MiB
    const size_t ABH_B  = (size_t)24 * PLANE * 4;      // 24 MiB

    if (ws_size >= H8_B + GRAY_B + AB_B + ABH_B) {
        uint4*   H8   = (uint4*)d_ws;
        __half*  gray = (__half*)((char*)d_ws + H8_B);
        __half2* ab   = (__half2*)((char*)d_ws + H8_B + GRAY_B);
        __half2* abH  = (__half2*)((char*)d_ws + H8_B + GRAY_B + AB_B);

        gfA <<<dim3(1, 128,  8), 256, 0, stream>>>(guide, inp, H8, gray);
        gfB <<<dim3(2,  32,  8), 256, 0, stream>>>(H8, ab);
        gfC1<<<dim3(1, 128, 24), 256, 0, stream>>>(ab, abH);
        gfC2<<<dim3(1,  32, 24), 256, 0, stream>>>(gray, abH, out);
    } else {
        float2* ab_ws = (float2*)d_ws;   // 50.3 MB
        gf_s1_fb<<<dim3(HW / TILE, HW / TILE, 8),  256, 0, stream>>>(guide, inp, ab_ws);
        gf_s2_fb<<<dim3(HW / TILE, HW / TILE, 24), 256, 0, stream>>>(guide, ab_ws, out);
    }
}